// Round 1
// baseline (357.614 us; speedup 1.0000x reference)
//
#include <hip/hip_runtime.h>
#include <hip/hip_bf16.h>

#define BS     4
#define NQ     10000
#define NV     13294
#define EMBED  256
#define HEADS  8
#define LEVELS 4
#define POINTS 4
#define DH     32

typedef __attribute__((ext_vector_type(8))) short short8;
typedef __attribute__((ext_vector_type(4))) float floatx4;

static __device__ __forceinline__ unsigned short f2b(float f) {
    __hip_bfloat16 h = __float2bfloat16(f);   // RNE
    return *(unsigned short*)&h;
}
static __device__ __forceinline__ float b2f(unsigned short u) {
    return __uint_as_float(((unsigned int)u) << 16);
}
static __device__ __forceinline__ unsigned int pk_bf16(float x, float y) {
    __hip_bfloat162 h = __float22bfloat162_rn(make_float2(x, y));  // v_cvt_pk_bf16_f32
    unsigned int u; __builtin_memcpy(&u, &h, 4); return u;
}

// ---------------------------------------------------------------------------
// Weight prep: transpose+cast to bf16 [N][K], concat (Woff|Ww) and (boff|bw).
// ---------------------------------------------------------------------------
__global__ __launch_bounds__(256) void prep_weights(
    const float* __restrict__ Wv,  const float* __restrict__ Woff,
    const float* __restrict__ boff,const float* __restrict__ Ww,
    const float* __restrict__ bw,  const float* __restrict__ Wo,
    unsigned short* __restrict__ Wvt, unsigned short* __restrict__ Wcatt,
    unsigned short* __restrict__ Wot, float* __restrict__ bcat)
{
    const int n = blockIdx.x;
    const int k = threadIdx.x;   // 0..255
    if (n < 256) {
        Wvt[n * 256 + k] = f2b(Wv[k * 256 + n]);
    } else if (n < 512) {
        Wcatt[(n - 256) * 256 + k] = f2b(Woff[k * 256 + (n - 256)]);
    } else if (n < 640) {
        Wcatt[(n - 256) * 256 + k] = f2b(Ww[k * 128 + (n - 512)]);
    } else {
        Wot[(n - 640) * 256 + k] = f2b(Wo[k * 256 + (n - 640)]);
    }
    if (n == 0) {
        for (int j = k; j < 384; j += 256)
            bcat[j] = (j < 256) ? boff[j] : bw[j - 256];
    }
}

// ---------------------------------------------------------------------------
// bf16 MFMA GEMM body: C[M x N] = A[M x 256] @ Bt^T + bias (Bt = [N][256] bf16)
// 128x128 tile / 256 threads. AF32: A is fp32, converted during staging.
// MODE 0: bf16 out; 2: fp32 out + residual.
//
// Software-pipelined (reg prefetch): tile k+1's global loads are issued
// right after the second barrier of step k, so their latency is covered by
// the MFMA phase of step k; the compiler's vmcnt(0) drain before the next
// iteration's first s_barrier lands exactly where the data is consumed.
// ---------------------------------------------------------------------------
#define ASTR 72   // 64 + 8 pad (ushorts)

template<int MODE, bool AF32>
static __device__ __forceinline__ void gemm_body(
    unsigned short* As, unsigned short* Bsh,
    const void* __restrict__ Aptr, int M,
    const unsigned short* __restrict__ Bt,
    const float* __restrict__ bias,
    void* __restrict__ Cv, int ldc,
    const float* __restrict__ residual,
    int mb, int nb)
{
    const int t  = threadIdx.x;
    const int m0 = mb * 128;
    const int n0 = nb * 128;

    const int wv   = t >> 6;
    const int lane = t & 63;
    const int wm   = (wv & 1) * 64;
    const int wn   = (wv >> 1) * 64;
    const int lr   = lane & 15;
    const int lk   = (lane >> 4) * 8;

    floatx4 acc[4][4] = {};

    const int ar = t >> 1;           // row 0..127
    const int ac = (t & 1) * 32;     // ushort col offset
    const int arow = m0 + ar;
    const bool aok = arow < M;

    // staging registers (live across the compute phase of the previous step)
    float4 af[8];   // AF32 path
    uint4  ab[4];   // bf16 path
    uint4  bb[4];

    auto load_tile = [&](int k0) {
        if (AF32) {
            if (aok) {
                const float4* s = (const float4*)((const float*)Aptr + (size_t)arow * 256 + k0 + ac);
                #pragma unroll
                for (int i = 0; i < 8; ++i) af[i] = s[i];
            } else {
                #pragma unroll
                for (int i = 0; i < 8; ++i) af[i] = make_float4(0.f, 0.f, 0.f, 0.f);
            }
        } else {
            if (aok) {
                const uint4* s = (const uint4*)((const unsigned short*)Aptr + (size_t)arow * 256 + k0 + ac);
                #pragma unroll
                for (int i = 0; i < 4; ++i) ab[i] = s[i];
            } else {
                #pragma unroll
                for (int i = 0; i < 4; ++i) ab[i] = make_uint4(0, 0, 0, 0);
            }
        }
        const uint4* bs = (const uint4*)(Bt + (size_t)(n0 + ar) * 256 + k0 + ac);
        #pragma unroll
        for (int i = 0; i < 4; ++i) bb[i] = bs[i];
    };

    load_tile(0);   // prologue

    #pragma unroll
    for (int k0 = 0; k0 < 256; k0 += 64) {
        // convert current A tile (waits on the prefetched loads, which have
        // had the whole previous compute phase to complete)
        uint4 aw[4];
        if (AF32) {
            #pragma unroll
            for (int i = 0; i < 4; ++i) {
                aw[i].x = pk_bf16(af[2 * i].x, af[2 * i].y);
                aw[i].y = pk_bf16(af[2 * i].z, af[2 * i].w);
                aw[i].z = pk_bf16(af[2 * i + 1].x, af[2 * i + 1].y);
                aw[i].w = pk_bf16(af[2 * i + 1].z, af[2 * i + 1].w);
            }
        } else {
            #pragma unroll
            for (int i = 0; i < 4; ++i) aw[i] = ab[i];
        }

        __syncthreads();   // previous compute done reading LDS
        {
            uint4* ad = (uint4*)&As[ar * ASTR + ac];
            #pragma unroll
            for (int i = 0; i < 4; ++i) ad[i] = aw[i];
            uint4* bd = (uint4*)&Bsh[ar * ASTR + ac];
            #pragma unroll
            for (int i = 0; i < 4; ++i) bd[i] = bb[i];
        }
        __syncthreads();   // lgkmcnt(0) drain here frees aw/bb for reuse

        if (k0 < 192) load_tile(k0 + 64);   // prefetch next tile (issue-only)

        #pragma unroll
        for (int kk = 0; kk < 64; kk += 32) {
            short8 bf[4];
            #pragma unroll
            for (int nt = 0; nt < 4; ++nt)
                bf[nt] = *(const short8*)&Bsh[(wn + nt * 16 + lr) * ASTR + kk + lk];
            #pragma unroll
            for (int mt = 0; mt < 4; ++mt) {
                const short8 afrag = *(const short8*)&As[(wm + mt * 16 + lr) * ASTR + kk + lk];
                #pragma unroll
                for (int nt = 0; nt < 4; ++nt)
                    acc[mt][nt] = __builtin_amdgcn_mfma_f32_16x16x32_bf16(afrag, bf[nt], acc[mt][nt], 0, 0, 0);
            }
        }
    }

    // epilogue: C/D layout col = lane&15, row = (lane>>4)*4 + reg
    const int rbase = m0 + wm + (lane >> 4) * 4;
    #pragma unroll
    for (int nt = 0; nt < 4; ++nt) {
        const int col = n0 + wn + nt * 16 + lr;
        const float bb_ = bias[col];
        #pragma unroll
        for (int mt = 0; mt < 4; ++mt) {
            #pragma unroll
            for (int r = 0; r < 4; ++r) {
                const int row = rbase + mt * 16 + r;
                if (row < M) {
                    float val = acc[mt][nt][r] + bb_;
                    if (MODE == 2) val += residual[(size_t)row * ldc + col];
                    if (MODE == 0)
                        ((unsigned short*)Cv)[(size_t)row * ldc + col] = f2b(val);
                    else
                        ((float*)Cv)[(size_t)row * ldc + col] = val;
                }
            }
        }
    }
}

// Fused GEMM-V + GEMM-proj (independent, one dispatch to fill the machine).
// blocks [0, 832): v = value @ Wv + bv          (416 m-blocks x 2 n-blocks)
// blocks [832,1771): proj = query @ Wcat + bcat (313 m-blocks x 3 n-blocks)
__global__ __launch_bounds__(256) void gemm_fused12(
    const float* __restrict__ value, const float* __restrict__ query,
    const unsigned short* __restrict__ Wvt, const unsigned short* __restrict__ Wcatt,
    const float* __restrict__ bv, const float* __restrict__ bcat,
    unsigned short* __restrict__ vout, unsigned short* __restrict__ projout)
{
    __shared__ __align__(16) unsigned short As[128 * ASTR];
    __shared__ __align__(16) unsigned short Bsh[128 * ASTR];
    const unsigned int bid = blockIdx.x;
    if (bid < 832u) {
        gemm_body<0, true>(As, Bsh, value, BS * NV, Wvt, bv, vout, 256, nullptr,
                           (int)(bid >> 1), (int)(bid & 1));
    } else {
        const unsigned int b2 = bid - 832u;
        gemm_body<0, true>(As, Bsh, query, BS * NQ, Wcatt, bcat, projout, 384, nullptr,
                           (int)(b2 / 3u), (int)(b2 % 3u));
    }
}

// out = msda @ Wo + bo + query  (fp32 out)
__global__ __launch_bounds__(256) void gemm_out(
    const unsigned short* __restrict__ msda, const unsigned short* __restrict__ Wot,
    const float* __restrict__ bo, float* __restrict__ out,
    const float* __restrict__ query)
{
    __shared__ __align__(16) unsigned short As[128 * ASTR];
    __shared__ __align__(16) unsigned short Bsh[128 * ASTR];
    gemm_body<2, false>(As, Bsh, msda, BS * NQ, Wot, bo, out, 256, query,
                        (int)blockIdx.x, (int)blockIdx.y);
}

// ---------------------------------------------------------------------------
// Fused softmax + bilinear sampling, two-phase (proj is bf16 now).
// ---------------------------------------------------------------------------
__global__ __launch_bounds__(256) void msda_sample(
    const unsigned short* __restrict__ v,
    const unsigned short* __restrict__ proj,
    const float* __restrict__ rp,
    unsigned short* __restrict__ out)
{
    __shared__ __align__(16) unsigned int taps[4 * 1056];  // 4 waves * 8 heads * 528 B

    const int wave = threadIdx.x >> 6;
    const int lane = threadIdx.x & 63;
    const int q = blockIdx.x * 4 + wave;
    const int b = blockIdx.y;
    const int rowq = b * NQ + q;
    const unsigned short* prow = proj + (size_t)rowq * 384;

    // ---- phase A: lane = h*8+i owns combos c = 2i, 2i+1 ----
    const int hA = lane >> 3;
    const int li = lane & 7;
    const int c0 = li * 2;

    const ushort2 lgu = *(const ushort2*)&prow[256 + hA * 16 + c0];
    const float lgx = b2f(lgu.x), lgy = b2f(lgu.y);
    float mx = fmaxf(lgx, lgy);
    mx = fmaxf(mx, __shfl_xor(mx, 1));
    mx = fmaxf(mx, __shfl_xor(mx, 2));
    mx = fmaxf(mx, __shfl_xor(mx, 4));
    const float e0 = __expf(lgx - mx);
    const float e1 = __expf(lgy - mx);
    float ssum = e0 + e1;
    ssum += __shfl_xor(ssum, 1);
    ssum += __shfl_xor(ssum, 2);
    ssum += __shfl_xor(ssum, 4);
    const float inv = 1.0f / ssum;

    const int l = c0 >> 2;   // both combos share the level
    const int Wl = (l == 0) ? 100 : (l == 1) ? 50 : (l == 2) ? 25 : 13;
    const int st = (l == 0) ? 0 : (l == 1) ? 10000 : (l == 2) ? 12500 : 13125;
    const int Hl = Wl;
    const float fW = (float)Wl, fH = (float)Hl;

    const float2 rxy = *(const float2*)&rp[((size_t)rowq * 4 + l) * 2];

    unsigned int* tbase = taps + wave * 1056 + hA * 132;

    #pragma unroll
    for (int cc = 0; cc < 2; ++cc) {
        const int c = c0 + cc;
        const ushort2 oxyu = *(const ushort2*)&prow[hA * 32 + c * 2];
        const float ox = b2f(oxyu.x), oy = b2f(oxyu.y);
        const float aww = (cc ? e1 : e0) * inv;
        const float x = fmaf(rxy.x, fW, ox) - 0.5f;
        const float y = fmaf(rxy.y, fH, oy) - 0.5f;
        const float x0f = floorf(x), y0f = floorf(y);
        const float fx = x - x0f, fy = y - y0f;
        const int ix = (int)x0f, iy = (int)y0f;
        const float wxv[2] = {1.f - fx, fx};
        const float wyv[2] = {1.f - fy, fy};

        uint4 ent[2];
        #pragma unroll
        for (int tp = 0; tp < 4; ++tp) {
            const int dy = tp >> 1, dx = tp & 1;
            const int xi = ix + dx, yi = iy + dy;
            const bool ok = (xi >= 0) && (xi < Wl) && (yi >= 0) && (yi < Hl);
            const int cx = min(max(xi, 0), Wl - 1);
            const int cy = min(max(yi, 0), Hl - 1);
            const unsigned int off = (unsigned int)(st + cy * Wl + cx) * 512u + (unsigned int)hA * 64u;
            const float w = ok ? wyv[dy] * wxv[dx] * aww : 0.f;
            ((unsigned int*)&ent[tp >> 1])[(tp & 1) * 2 + 0] = off;
            ((unsigned int*)&ent[tp >> 1])[(tp & 1) * 2 + 1] = __float_as_uint(w);
        }
        *(uint4*)&tbase[(c * 4 + 0) * 2] = ent[0];
        *(uint4*)&tbase[(c * 4 + 2) * 2] = ent[1];
    }

    __syncthreads();

    // ---- phase B: lane = h*8+i owns dims i*4..i*4+3; saddr-form gathers ----
    const int h = lane >> 3;
    const unsigned int lane_off = (unsigned int)(lane & 7) * 8u;
    const char* vbase = (const char*)v + (size_t)b * NV * 512;   // wave-uniform
    const uint4* tp4 = (const uint4*)(taps + wave * 1056 + h * 132);

    float a0 = 0.f, a1 = 0.f, a2 = 0.f, a3 = 0.f;
    #pragma unroll 8
    for (int j = 0; j < 32; ++j) {
        const uint4 ee = tp4[j];
        const uint2 g0 = *(const uint2*)(vbase + (ee.x + lane_off));
        const uint2 g1 = *(const uint2*)(vbase + (ee.z + lane_off));
        const float w0 = __uint_as_float(ee.y);
        const float w1 = __uint_as_float(ee.w);
        a0 = fmaf(w0, __uint_as_float(g0.x << 16), a0);
        a1 = fmaf(w0, __uint_as_float(g0.x & 0xFFFF0000u), a1);
        a2 = fmaf(w0, __uint_as_float(g0.y << 16), a2);
        a3 = fmaf(w0, __uint_as_float(g0.y & 0xFFFF0000u), a3);
        a0 = fmaf(w1, __uint_as_float(g1.x << 16), a0);
        a1 = fmaf(w1, __uint_as_float(g1.x & 0xFFFF0000u), a1);
        a2 = fmaf(w1, __uint_as_float(g1.y << 16), a2);
        a3 = fmaf(w1, __uint_as_float(g1.y & 0xFFFF0000u), a3);
    }

    ushort4 o;
    o.x = f2b(a0); o.y = f2b(a1); o.z = f2b(a2); o.w = f2b(a3);
    *(ushort4*)&out[(size_t)rowq * 256 + h * 32 + (lane & 7) * 4] = o;
}

// ---------------------------------------------------------------------------
// kernel_launch
// ---------------------------------------------------------------------------
extern "C" void kernel_launch(void* const* d_in, const int* in_sizes, int n_in,
                              void* d_out, int out_size, void* d_ws, size_t ws_size,
                              hipStream_t stream) {
    const float* query = (const float*)d_in[0];
    const float* value = (const float*)d_in[1];
    const float* rp    = (const float*)d_in[2];
    const float* Wv    = (const float*)d_in[4];
    const float* bv    = (const float*)d_in[5];
    const float* Woff  = (const float*)d_in[6];
    const float* boff  = (const float*)d_in[7];
    const float* Ww    = (const float*)d_in[8];
    const float* bw    = (const float*)d_in[9];
    const float* Wo    = (const float*)d_in[10];
    const float* bo    = (const float*)d_in[11];
    float* out = (float*)d_out;

    const int Mv = BS * NV;   // 53176
    const int Mq = BS * NQ;   // 40000

    char* ws = (char*)d_ws;
    const size_t SZ_MSDA = (size_t)Mq * 256 * 2;   // 20,480,000
    const size_t SZ_V    = (size_t)Mv * 256 * 2;   // 27,226,112
    const size_t SZ_PROJ = (size_t)Mq * 384 * 2;   // 30,720,000
    unsigned short* msda  = (unsigned short*)(ws);
    unsigned short* v_bf  = (unsigned short*)(ws + SZ_MSDA);
    unsigned short* proj  = (unsigned short*)(ws + SZ_MSDA + SZ_V);
    char* wp = ws + SZ_MSDA + SZ_V + SZ_PROJ;
    unsigned short* Wvt   = (unsigned short*)(wp);
    unsigned short* Wcatt = (unsigned short*)(wp + 256 * 256 * 2);
    unsigned short* Wot   = (unsigned short*)(wp + 256 * 256 * 2 + 384 * 256 * 2);
    float*          bcat  = (float*)(wp + 256 * 256 * 2 + 384 * 256 * 2 + 256 * 256 * 2);

    prep_weights<<<896, 256, 0, stream>>>(Wv, Woff, boff, Ww, bw, Wo, Wvt, Wcatt, Wot, bcat);

    // v = value @ Wv + bv (bf16) AND proj = query @ [Woff|Ww] + bias (bf16)
    gemm_fused12<<<832 + 939, 256, 0, stream>>>(
        value, query, Wvt, Wcatt, bv, bcat, v_bf, proj);

    // softmax + sampling -> msda (bf16)
    msda_sample<<<dim3(NQ / 4, BS), 256, 0, stream>>>(v_bf, proj, rp, msda);

    // out = msda @ Wo + bo + query
    gemm_out<<<dim3((Mq + 127) / 128, 2), 256, 0, stream>>>(msda, Wot, bo, out, query);
}

// Round 2
// 319.317 us; speedup vs baseline: 1.1199x; 1.1199x over previous
//
#include <hip/hip_runtime.h>
#include <hip/hip_bf16.h>

#define BS     4
#define NQ     10000
#define NV     13294
#define EMBED  256
#define HEADS  8
#define LEVELS 4
#define POINTS 4
#define DH     32

// padded row counts (multiples of 128) so GEMM A-tiles can be read unguarded
#define MV_PAD 53248   // ceil(4*13294/128)*128
#define MQ_PAD 40064   // ceil(4*10000/128)*128

typedef __attribute__((ext_vector_type(8))) short short8;
typedef __attribute__((ext_vector_type(4))) float floatx4;

static __device__ __forceinline__ unsigned short f2b(float f) {
    __hip_bfloat16 h = __float2bfloat16(f);   // RNE
    return *(unsigned short*)&h;
}
static __device__ __forceinline__ float b2f(unsigned short u) {
    return __uint_as_float(((unsigned int)u) << 16);
}
static __device__ __forceinline__ unsigned int pk_bf16(float x, float y) {
    __hip_bfloat162 h = __float22bfloat162_rn(make_float2(x, y));  // v_cvt_pk_bf16_f32
    unsigned int u; __builtin_memcpy(&u, &h, 4); return u;
}

// async global->LDS, 16B per lane. LDS dest is wave-uniform base + lane*16.
static __device__ __forceinline__ void gload_lds16(const unsigned short* g, unsigned short* l) {
    __builtin_amdgcn_global_load_lds(
        (const __attribute__((address_space(1))) void*)g,
        (__attribute__((address_space(3))) void*)l,
        16, 0, 0);
}

// ---------------------------------------------------------------------------
// prep_convert:
//  blocks [0,896): weight transpose+cast
//  blocks [896, 896+CONV_BLOCKS): streaming fp32->bf16 of value and query
// ---------------------------------------------------------------------------
#define CONV_BLOCKS 2048

__global__ __launch_bounds__(256) void prep_convert(
    const float* __restrict__ Wv,  const float* __restrict__ Woff,
    const float* __restrict__ boff,const float* __restrict__ Ww,
    const float* __restrict__ bw,  const float* __restrict__ Wo,
    const float* __restrict__ value, const float* __restrict__ query,
    unsigned short* __restrict__ Wvt, unsigned short* __restrict__ Wcatt,
    unsigned short* __restrict__ Wot, float* __restrict__ bcat,
    unsigned short* __restrict__ v16, unsigned short* __restrict__ q16)
{
    const int n = blockIdx.x;
    const int k = threadIdx.x;   // 0..255
    if (n < 896) {
        if (n < 256) {
            Wvt[n * 256 + k] = f2b(Wv[k * 256 + n]);
        } else if (n < 512) {
            Wcatt[(n - 256) * 256 + k] = f2b(Woff[k * 256 + (n - 256)]);
        } else if (n < 640) {
            Wcatt[(n - 256) * 256 + k] = f2b(Ww[k * 128 + (n - 512)]);
        } else {
            Wot[(n - 640) * 256 + k] = f2b(Wo[k * 256 + (n - 640)]);
        }
        if (n == 0) {
            for (int j = k; j < 384; j += 256)
                bcat[j] = (j < 256) ? boff[j] : bw[j - 256];
        }
        return;
    }
    // convert in units of 8 floats (two float4 loads -> one uint4 store)
    const long long NV8 = (long long)BS * NV * 256 / 8;   // 1,701,632
    const long long NQ8 = (long long)BS * NQ * 256 / 8;   // 1,280,000
    const long long stride = (long long)CONV_BLOCKS * 256;
    for (long long u = (long long)(n - 896) * 256 + k; u < NV8 + NQ8; u += stride) {
        const float4* s;
        unsigned short* d;
        if (u < NV8) { s = (const float4*)value + u * 2;         d = v16 + u * 8; }
        else         { s = (const float4*)query + (u - NV8) * 2; d = q16 + (u - NV8) * 8; }
        const float4 f0 = s[0], f1 = s[1];
        uint4 o;
        o.x = pk_bf16(f0.x, f0.y);
        o.y = pk_bf16(f0.z, f0.w);
        o.z = pk_bf16(f1.x, f1.y);
        o.w = pk_bf16(f1.z, f1.w);
        *(uint4*)d = o;
    }
}

// ---------------------------------------------------------------------------
// bf16 MFMA GEMM body: C[M x N] = A[M x 256] @ Bt^T + bias (all bf16 inputs).
// 128x128 tile / 256 threads / BK=64. m97 structure: global_load_lds width-16
// staging into linear LDS. Rule-21 both-sides XOR swizzle: inverse-swizzled
// global source + swizzled ds_read (byte ^= (row&7)<<4 within each 128B row)
// -> 2-way max bank aliasing on the fragment reads (free).
// A must be padded so rows [mb*128, mb*128+128) are readable.
// MODE 0: bf16 out; 2: fp32 out + residual.
// ---------------------------------------------------------------------------
template<int MODE>
static __device__ __forceinline__ void gemm_body(
    unsigned short* As, unsigned short* Bs,
    const unsigned short* __restrict__ A, int M,
    const unsigned short* __restrict__ Bt,
    const float* __restrict__ bias,
    void* __restrict__ Cv, int ldc,
    const float* __restrict__ residual,
    int mb, int nb)
{
    const int t    = threadIdx.x;
    const int w    = t >> 6;
    const int lane = t & 63;
    const int m0 = mb * 128;
    const int n0 = nb * 128;
    const int wm = (w & 1) * 64;
    const int wn = (w >> 1) * 64;
    const int lr = lane & 15;
    const int lk = (lane >> 4) * 8;

    // staging geometry: wave w, issue j covers LDS rows w*8+j*32 .. +8;
    // lane covers row w*8+j*32+(lane>>3), 16B chunk (lane&7).
    // Source column chunk pre-swizzled: chunk (lane&7)^(row&7), row&7=lane>>3.
    const int srow = w * 8 + (lane >> 3);
    const int scol = ((lane & 7) ^ (lane >> 3)) * 8;
    const unsigned short* ga = A  + (size_t)(m0 + srow) * 256 + scol;
    const unsigned short* gb = Bt + (size_t)(n0 + srow) * 256 + scol;
    unsigned short* lA = As + w * 512;   // + j*2048
    unsigned short* lB = Bs + w * 512;

    floatx4 acc[4][4] = {};

    for (int k0 = 0; k0 < 256; k0 += 64) {
        __syncthreads();   // previous tile's LDS reads complete before overwrite
        #pragma unroll
        for (int j = 0; j < 4; ++j) {
            gload_lds16(ga + (size_t)j * 32 * 256 + k0, lA + j * 2048);
            gload_lds16(gb + (size_t)j * 32 * 256 + k0, lB + j * 2048);
        }
        __syncthreads();   // vmcnt(0) drain: tile resident in LDS

        #pragma unroll
        for (int kk = 0; kk < 64; kk += 32) {
            short8 bf[4];
            #pragma unroll
            for (int nt = 0; nt < 4; ++nt) {
                const int row = wn + nt * 16 + lr;
                const int cb  = ((kk + lk) * 2) ^ ((row & 7) << 4);
                bf[nt] = *(const short8*)((const char*)Bs + row * 128 + cb);
            }
            #pragma unroll
            for (int mt = 0; mt < 4; ++mt) {
                const int row = wm + mt * 16 + lr;
                const int cb  = ((kk + lk) * 2) ^ ((row & 7) << 4);
                const short8 af = *(const short8*)((const char*)As + row * 128 + cb);
                #pragma unroll
                for (int nt = 0; nt < 4; ++nt)
                    acc[mt][nt] = __builtin_amdgcn_mfma_f32_16x16x32_bf16(af, bf[nt], acc[mt][nt], 0, 0, 0);
            }
        }
    }

    // epilogue: C/D layout col = lane&15, row = (lane>>4)*4 + reg
    const int rbase = m0 + wm + (lane >> 4) * 4;
    #pragma unroll
    for (int nt = 0; nt < 4; ++nt) {
        const int col = n0 + wn + nt * 16 + lr;
        const float bb_ = bias[col];
        #pragma unroll
        for (int mt = 0; mt < 4; ++mt) {
            #pragma unroll
            for (int r = 0; r < 4; ++r) {
                const int row = rbase + mt * 16 + r;
                if (row < M) {
                    float val = acc[mt][nt][r] + bb_;
                    if (MODE == 2) val += residual[(size_t)row * ldc + col];
                    if (MODE == 0)
                        ((unsigned short*)Cv)[(size_t)row * ldc + col] = f2b(val);
                    else
                        ((float*)Cv)[(size_t)row * ldc + col] = val;
                }
            }
        }
    }
}

// Fused GEMM-V + GEMM-proj (independent, one dispatch to fill the machine).
// blocks [0, 832): v = v16 @ Wv + bv            (416 m-blocks x 2 n-blocks)
// blocks [832,1771): proj = q16 @ Wcat + bcat   (313 m-blocks x 3 n-blocks)
__global__ __launch_bounds__(256) void gemm_fused12(
    const unsigned short* __restrict__ v16, const unsigned short* __restrict__ q16,
    const unsigned short* __restrict__ Wvt, const unsigned short* __restrict__ Wcatt,
    const float* __restrict__ bv, const float* __restrict__ bcat,
    unsigned short* __restrict__ vout, unsigned short* __restrict__ projout)
{
    __shared__ __align__(16) unsigned short As[128 * 64];
    __shared__ __align__(16) unsigned short Bs[128 * 64];
    const unsigned int bid = blockIdx.x;
    if (bid < 832u) {
        gemm_body<0>(As, Bs, v16, BS * NV, Wvt, bv, vout, 256, nullptr,
                     (int)(bid >> 1), (int)(bid & 1));
    } else {
        const unsigned int b2 = bid - 832u;
        gemm_body<0>(As, Bs, q16, BS * NQ, Wcatt, bcat, projout, 384, nullptr,
                     (int)(b2 / 3u), (int)(b2 % 3u));
    }
}

// out = msda @ Wo + bo + query  (fp32 out)
__global__ __launch_bounds__(256) void gemm_out(
    const unsigned short* __restrict__ msda, const unsigned short* __restrict__ Wot,
    const float* __restrict__ bo, float* __restrict__ out,
    const float* __restrict__ query)
{
    __shared__ __align__(16) unsigned short As[128 * 64];
    __shared__ __align__(16) unsigned short Bs[128 * 64];
    gemm_body<2>(As, Bs, msda, BS * NQ, Wot, bo, out, 256, query,
                 (int)blockIdx.x, (int)blockIdx.y);
}

// ---------------------------------------------------------------------------
// Fused softmax + bilinear sampling, two-phase (proj is bf16).
// ---------------------------------------------------------------------------
__global__ __launch_bounds__(256) void msda_sample(
    const unsigned short* __restrict__ v,
    const unsigned short* __restrict__ proj,
    const float* __restrict__ rp,
    unsigned short* __restrict__ out)
{
    __shared__ __align__(16) unsigned int taps[4 * 1056];  // 4 waves * 8 heads * 528 B

    const int wave = threadIdx.x >> 6;
    const int lane = threadIdx.x & 63;
    const int q = blockIdx.x * 4 + wave;
    const int b = blockIdx.y;
    const int rowq = b * NQ + q;
    const unsigned short* prow = proj + (size_t)rowq * 384;

    // ---- phase A: lane = h*8+i owns combos c = 2i, 2i+1 ----
    const int hA = lane >> 3;
    const int li = lane & 7;
    const int c0 = li * 2;

    const ushort2 lgu = *(const ushort2*)&prow[256 + hA * 16 + c0];
    const float lgx = b2f(lgu.x), lgy = b2f(lgu.y);
    float mx = fmaxf(lgx, lgy);
    mx = fmaxf(mx, __shfl_xor(mx, 1));
    mx = fmaxf(mx, __shfl_xor(mx, 2));
    mx = fmaxf(mx, __shfl_xor(mx, 4));
    const float e0 = __expf(lgx - mx);
    const float e1 = __expf(lgy - mx);
    float ssum = e0 + e1;
    ssum += __shfl_xor(ssum, 1);
    ssum += __shfl_xor(ssum, 2);
    ssum += __shfl_xor(ssum, 4);
    const float inv = 1.0f / ssum;

    const int l = c0 >> 2;   // both combos share the level
    const int Wl = (l == 0) ? 100 : (l == 1) ? 50 : (l == 2) ? 25 : 13;
    const int st = (l == 0) ? 0 : (l == 1) ? 10000 : (l == 2) ? 12500 : 13125;
    const int Hl = Wl;
    const float fW = (float)Wl, fH = (float)Hl;

    const float2 rxy = *(const float2*)&rp[((size_t)rowq * 4 + l) * 2];

    unsigned int* tbase = taps + wave * 1056 + hA * 132;

    #pragma unroll
    for (int cc = 0; cc < 2; ++cc) {
        const int c = c0 + cc;
        const ushort2 oxyu = *(const ushort2*)&prow[hA * 32 + c * 2];
        const float ox = b2f(oxyu.x), oy = b2f(oxyu.y);
        const float aww = (cc ? e1 : e0) * inv;
        const float x = fmaf(rxy.x, fW, ox) - 0.5f;
        const float y = fmaf(rxy.y, fH, oy) - 0.5f;
        const float x0f = floorf(x), y0f = floorf(y);
        const float fx = x - x0f, fy = y - y0f;
        const int ix = (int)x0f, iy = (int)y0f;
        const float wxv[2] = {1.f - fx, fx};
        const float wyv[2] = {1.f - fy, fy};

        uint4 ent[2];
        #pragma unroll
        for (int tp = 0; tp < 4; ++tp) {
            const int dy = tp >> 1, dx = tp & 1;
            const int xi = ix + dx, yi = iy + dy;
            const bool ok = (xi >= 0) && (xi < Wl) && (yi >= 0) && (yi < Hl);
            const int cx = min(max(xi, 0), Wl - 1);
            const int cy = min(max(yi, 0), Hl - 1);
            const unsigned int off = (unsigned int)(st + cy * Wl + cx) * 512u + (unsigned int)hA * 64u;
            const float w = ok ? wyv[dy] * wxv[dx] * aww : 0.f;
            ((unsigned int*)&ent[tp >> 1])[(tp & 1) * 2 + 0] = off;
            ((unsigned int*)&ent[tp >> 1])[(tp & 1) * 2 + 1] = __float_as_uint(w);
        }
        *(uint4*)&tbase[(c * 4 + 0) * 2] = ent[0];
        *(uint4*)&tbase[(c * 4 + 2) * 2] = ent[1];
    }

    __syncthreads();

    // ---- phase B: lane = h*8+i owns dims i*4..i*4+3; saddr-form gathers ----
    const int h = lane >> 3;
    const unsigned int lane_off = (unsigned int)(lane & 7) * 8u;
    const char* vbase = (const char*)v + (size_t)b * NV * 512;   // wave-uniform
    const uint4* tp4 = (const uint4*)(taps + wave * 1056 + h * 132);

    float a0 = 0.f, a1 = 0.f, a2 = 0.f, a3 = 0.f;
    #pragma unroll 8
    for (int j = 0; j < 32; ++j) {
        const uint4 ee = tp4[j];
        const uint2 g0 = *(const uint2*)(vbase + (ee.x + lane_off));
        const uint2 g1 = *(const uint2*)(vbase + (ee.z + lane_off));
        const float w0 = __uint_as_float(ee.y);
        const float w1 = __uint_as_float(ee.w);
        a0 = fmaf(w0, __uint_as_float(g0.x << 16), a0);
        a1 = fmaf(w0, __uint_as_float(g0.x & 0xFFFF0000u), a1);
        a2 = fmaf(w0, __uint_as_float(g0.y << 16), a2);
        a3 = fmaf(w0, __uint_as_float(g0.y & 0xFFFF0000u), a3);
        a0 = fmaf(w1, __uint_as_float(g1.x << 16), a0);
        a1 = fmaf(w1, __uint_as_float(g1.x & 0xFFFF0000u), a1);
        a2 = fmaf(w1, __uint_as_float(g1.y << 16), a2);
        a3 = fmaf(w1, __uint_as_float(g1.y & 0xFFFF0000u), a3);
    }

    ushort4 o;
    o.x = f2b(a0); o.y = f2b(a1); o.z = f2b(a2); o.w = f2b(a3);
    *(ushort4*)&out[(size_t)rowq * 256 + h * 32 + (lane & 7) * 4] = o;
}

// ---------------------------------------------------------------------------
// kernel_launch
// ---------------------------------------------------------------------------
extern "C" void kernel_launch(void* const* d_in, const int* in_sizes, int n_in,
                              void* d_out, int out_size, void* d_ws, size_t ws_size,
                              hipStream_t stream) {
    const float* query = (const float*)d_in[0];
    const float* value = (const float*)d_in[1];
    const float* rp    = (const float*)d_in[2];
    const float* Wv    = (const float*)d_in[4];
    const float* bv    = (const float*)d_in[5];
    const float* Woff  = (const float*)d_in[6];
    const float* boff  = (const float*)d_in[7];
    const float* Ww    = (const float*)d_in[8];
    const float* bw    = (const float*)d_in[9];
    const float* Wo    = (const float*)d_in[10];
    const float* bo    = (const float*)d_in[11];
    float* out = (float*)d_out;

    const int Mq = BS * NQ;   // 40000

    char* ws = (char*)d_ws;
    const size_t SZ_MSDA = (size_t)MQ_PAD * 256 * 2;   // 20,512,768 (padded rows)
    const size_t SZ_VIN  = (size_t)MV_PAD * 256 * 2;   // 27,262,976 (bf16 value, padded)
    const size_t SZ_QIN  = (size_t)MQ_PAD * 256 * 2;   // 20,512,768 (bf16 query, padded)
    const size_t SZ_VPR  = (size_t)BS * NV * 256 * 2;  // 27,226,112 (projected v)
    const size_t SZ_PROJ = (size_t)Mq * 384 * 2;       // 30,720,000

    unsigned short* msda  = (unsigned short*)(ws);
    unsigned short* v16   = (unsigned short*)(ws + SZ_MSDA);
    unsigned short* q16   = (unsigned short*)(ws + SZ_MSDA + SZ_VIN);
    unsigned short* v_prj = (unsigned short*)(ws + SZ_MSDA + SZ_VIN + SZ_QIN);
    unsigned short* proj  = (unsigned short*)(ws + SZ_MSDA + SZ_VIN + SZ_QIN + SZ_VPR);
    char* wp = ws + SZ_MSDA + SZ_VIN + SZ_QIN + SZ_VPR + SZ_PROJ;
    unsigned short* Wvt   = (unsigned short*)(wp);
    unsigned short* Wcatt = (unsigned short*)(wp + 256 * 256 * 2);
    unsigned short* Wot   = (unsigned short*)(wp + 256 * 256 * 2 + 384 * 256 * 2);
    float*          bcat  = (float*)(wp + 256 * 256 * 2 + 384 * 256 * 2 + 256 * 256 * 2);

    // weights transpose/cast + value/query fp32->bf16 streaming convert
    prep_convert<<<896 + CONV_BLOCKS, 256, 0, stream>>>(
        Wv, Woff, boff, Ww, bw, Wo, value, query,
        Wvt, Wcatt, Wot, bcat, v16, q16);

    // v_prj = v16 @ Wv + bv (bf16) AND proj = q16 @ [Woff|Ww] + bias (bf16)
    gemm_fused12<<<832 + 939, 256, 0, stream>>>(
        v16, q16, Wvt, Wcatt, bv, bcat, v_prj, proj);

    // softmax + sampling -> msda (bf16)
    msda_sample<<<dim3(NQ / 4, BS), 256, 0, stream>>>(v_prj, proj, rp, msda);

    // out = msda @ Wo + bo + query
    gemm_out<<<dim3((Mq + 127) / 128, 2), 256, 0, stream>>>(msda, Wot, bo, out, query);
}

// Round 3
// 316.161 us; speedup vs baseline: 1.1311x; 1.0100x over previous
//
#include <hip/hip_runtime.h>
#include <hip/hip_bf16.h>

#define BS     4
#define NQ     10000
#define NV     13294
#define EMBED  256
#define HEADS  8
#define LEVELS 4
#define POINTS 4
#define DH     32

// padded row counts (multiples of 128) so GEMM A-tiles can be read unguarded
#define MV_PAD 53248   // ceil(4*13294/128)*128
#define MQ_PAD 40064   // ceil(4*10000/128)*128

typedef __attribute__((ext_vector_type(8))) short short8;
typedef __attribute__((ext_vector_type(4))) float floatx4;
#if __has_builtin(__builtin_amdgcn_fdot2_f32_bf16)
typedef __attribute__((ext_vector_type(2))) __bf16 bf16x2_t;
#define HAVE_DOT2 1
#else
#define HAVE_DOT2 0
#endif

static __device__ __forceinline__ unsigned short f2b(float f) {
    __hip_bfloat16 h = __float2bfloat16(f);   // RNE
    return *(unsigned short*)&h;
}
static __device__ __forceinline__ float b2f(unsigned short u) {
    return __uint_as_float(((unsigned int)u) << 16);
}
static __device__ __forceinline__ unsigned int pk_bf16(float x, float y) {
    __hip_bfloat162 h = __float22bfloat162_rn(make_float2(x, y));  // v_cvt_pk_bf16_f32
    unsigned int u; __builtin_memcpy(&u, &h, 4); return u;
}

// async global->LDS, 16B per lane. LDS dest is wave-uniform base + lane*16.
static __device__ __forceinline__ void gload_lds16(const unsigned short* g, unsigned short* l) {
    __builtin_amdgcn_global_load_lds(
        (const __attribute__((address_space(1))) void*)g,
        (__attribute__((address_space(3))) void*)l,
        16, 0, 0);
}

// ---------------------------------------------------------------------------
// prep_convert:
//  blocks [0,896): weight transpose+cast
//  blocks [896, 896+CONV_BLOCKS): streaming fp32->bf16 of value and query
// ---------------------------------------------------------------------------
#define CONV_BLOCKS 2048

__global__ __launch_bounds__(256) void prep_convert(
    const float* __restrict__ Wv,  const float* __restrict__ Woff,
    const float* __restrict__ boff,const float* __restrict__ Ww,
    const float* __restrict__ bw,  const float* __restrict__ Wo,
    const float* __restrict__ value, const float* __restrict__ query,
    unsigned short* __restrict__ Wvt, unsigned short* __restrict__ Wcatt,
    unsigned short* __restrict__ Wot, float* __restrict__ bcat,
    unsigned short* __restrict__ v16, unsigned short* __restrict__ q16)
{
    const int n = blockIdx.x;
    const int k = threadIdx.x;   // 0..255
    if (n < 896) {
        if (n < 256) {
            Wvt[n * 256 + k] = f2b(Wv[k * 256 + n]);
        } else if (n < 512) {
            Wcatt[(n - 256) * 256 + k] = f2b(Woff[k * 256 + (n - 256)]);
        } else if (n < 640) {
            Wcatt[(n - 256) * 256 + k] = f2b(Ww[k * 128 + (n - 512)]);
        } else {
            Wot[(n - 640) * 256 + k] = f2b(Wo[k * 256 + (n - 640)]);
        }
        if (n == 0) {
            for (int j = k; j < 384; j += 256)
                bcat[j] = (j < 256) ? boff[j] : bw[j - 256];
        }
        return;
    }
    // convert in units of 8 floats (two float4 loads -> one uint4 store)
    const long long NV8 = (long long)BS * NV * 256 / 8;   // 1,701,632
    const long long NQ8 = (long long)BS * NQ * 256 / 8;   // 1,280,000
    const long long stride = (long long)CONV_BLOCKS * 256;
    for (long long u = (long long)(n - 896) * 256 + k; u < NV8 + NQ8; u += stride) {
        const float4* s;
        unsigned short* d;
        if (u < NV8) { s = (const float4*)value + u * 2;         d = v16 + u * 8; }
        else         { s = (const float4*)query + (u - NV8) * 2; d = q16 + (u - NV8) * 8; }
        const float4 f0 = s[0], f1 = s[1];
        uint4 o;
        o.x = pk_bf16(f0.x, f0.y);
        o.y = pk_bf16(f0.z, f0.w);
        o.z = pk_bf16(f1.x, f1.y);
        o.w = pk_bf16(f1.z, f1.w);
        *(uint4*)d = o;
    }
}

// ---------------------------------------------------------------------------
// bf16 MFMA GEMM body: C[M x N] = A[M x 256] @ Bt^T + bias (all bf16 inputs).
// 128x128 tile / 256 threads / BK=64. m97 structure: global_load_lds width-16
// staging into linear LDS. Rule-21 both-sides XOR swizzle: inverse-swizzled
// global source + swizzled ds_read (byte ^= (row&7)<<4 within each 128B row).
// A must be padded so rows [mb*128, mb*128+128) are readable.
// MODE 0: bf16 out; 2: fp32 out + residual.
// ---------------------------------------------------------------------------
template<int MODE>
static __device__ __forceinline__ void gemm_body(
    unsigned short* As, unsigned short* Bs,
    const unsigned short* __restrict__ A, int M,
    const unsigned short* __restrict__ Bt,
    const float* __restrict__ bias,
    void* __restrict__ Cv, int ldc,
    const float* __restrict__ residual,
    int mb, int nb)
{
    const int t    = threadIdx.x;
    const int w    = t >> 6;
    const int lane = t & 63;
    const int m0 = mb * 128;
    const int n0 = nb * 128;
    const int wm = (w & 1) * 64;
    const int wn = (w >> 1) * 64;
    const int lr = lane & 15;
    const int lk = (lane >> 4) * 8;

    // staging geometry: wave w, issue j covers LDS rows w*8+j*32 .. +8;
    // lane covers row w*8+j*32+(lane>>3), 16B chunk (lane&7).
    // Source column chunk pre-swizzled: chunk (lane&7)^(row&7), row&7=lane>>3.
    const int srow = w * 8 + (lane >> 3);
    const int scol = ((lane & 7) ^ (lane >> 3)) * 8;
    const unsigned short* ga = A  + (size_t)(m0 + srow) * 256 + scol;
    const unsigned short* gb = Bt + (size_t)(n0 + srow) * 256 + scol;
    unsigned short* lA = As + w * 512;   // + j*2048
    unsigned short* lB = Bs + w * 512;

    floatx4 acc[4][4] = {};

    for (int k0 = 0; k0 < 256; k0 += 64) {
        __syncthreads();   // previous tile's LDS reads complete before overwrite
        #pragma unroll
        for (int j = 0; j < 4; ++j) {
            gload_lds16(ga + (size_t)j * 32 * 256 + k0, lA + j * 2048);
            gload_lds16(gb + (size_t)j * 32 * 256 + k0, lB + j * 2048);
        }
        __syncthreads();   // vmcnt(0) drain: tile resident in LDS

        #pragma unroll
        for (int kk = 0; kk < 64; kk += 32) {
            short8 bf[4];
            #pragma unroll
            for (int nt = 0; nt < 4; ++nt) {
                const int row = wn + nt * 16 + lr;
                const int cb  = ((kk + lk) * 2) ^ ((row & 7) << 4);
                bf[nt] = *(const short8*)((const char*)Bs + row * 128 + cb);
            }
            #pragma unroll
            for (int mt = 0; mt < 4; ++mt) {
                const int row = wm + mt * 16 + lr;
                const int cb  = ((kk + lk) * 2) ^ ((row & 7) << 4);
                const short8 af = *(const short8*)((const char*)As + row * 128 + cb);
                #pragma unroll
                for (int nt = 0; nt < 4; ++nt)
                    acc[mt][nt] = __builtin_amdgcn_mfma_f32_16x16x32_bf16(af, bf[nt], acc[mt][nt], 0, 0, 0);
            }
        }
    }

    // epilogue: C/D layout col = lane&15, row = (lane>>4)*4 + reg
    const int rbase = m0 + wm + (lane >> 4) * 4;
    #pragma unroll
    for (int nt = 0; nt < 4; ++nt) {
        const int col = n0 + wn + nt * 16 + lr;
        const float bb_ = bias[col];
        #pragma unroll
        for (int mt = 0; mt < 4; ++mt) {
            #pragma unroll
            for (int r = 0; r < 4; ++r) {
                const int row = rbase + mt * 16 + r;
                if (row < M) {
                    float val = acc[mt][nt][r] + bb_;
                    if (MODE == 2) val += residual[(size_t)row * ldc + col];
                    if (MODE == 0)
                        ((unsigned short*)Cv)[(size_t)row * ldc + col] = f2b(val);
                    else
                        ((float*)Cv)[(size_t)row * ldc + col] = val;
                }
            }
        }
    }
}

// Fused GEMM-V + GEMM-proj (independent, one dispatch to fill the machine).
__global__ __launch_bounds__(256) void gemm_fused12(
    const unsigned short* __restrict__ v16, const unsigned short* __restrict__ q16,
    const unsigned short* __restrict__ Wvt, const unsigned short* __restrict__ Wcatt,
    const float* __restrict__ bv, const float* __restrict__ bcat,
    unsigned short* __restrict__ vout, unsigned short* __restrict__ projout)
{
    __shared__ __align__(16) unsigned short As[128 * 64];
    __shared__ __align__(16) unsigned short Bs[128 * 64];
    const unsigned int bid = blockIdx.x;
    if (bid < 832u) {
        gemm_body<0>(As, Bs, v16, BS * NV, Wvt, bv, vout, 256, nullptr,
                     (int)(bid >> 1), (int)(bid & 1));
    } else {
        const unsigned int b2 = bid - 832u;
        gemm_body<0>(As, Bs, q16, BS * NQ, Wcatt, bcat, projout, 384, nullptr,
                     (int)(b2 / 3u), (int)(b2 % 3u));
    }
}

// out = msda @ Wo + bo + query  (fp32 out)
__global__ __launch_bounds__(256) void gemm_out(
    const unsigned short* __restrict__ msda, const unsigned short* __restrict__ Wot,
    const float* __restrict__ bo, float* __restrict__ out,
    const float* __restrict__ query)
{
    __shared__ __align__(16) unsigned short As[128 * 64];
    __shared__ __align__(16) unsigned short Bs[128 * 64];
    gemm_body<2>(As, Bs, msda, BS * NQ, Wot, bo, out, 256, query,
                 (int)blockIdx.x, (int)blockIdx.y);
}

// ---------------------------------------------------------------------------
// Fused softmax + bilinear sampling.
// Tap entry (16 B): {off_tap0, off_tap1, pk_bf16(w0,w1), pad}. Inner loop
// consumes both taps of a pair with 4x v_perm_b32 + 4x v_dot2_f32_bf16.
// Taps are produced/consumed by the SAME wave -> no __syncthreads needed,
// only an LDS drain (waves run decoupled).
// ---------------------------------------------------------------------------
__global__ __launch_bounds__(256) void msda_sample(
    const unsigned short* __restrict__ v,
    const unsigned short* __restrict__ proj,
    const float* __restrict__ rp,
    unsigned short* __restrict__ out)
{
    __shared__ __align__(16) unsigned int taps[4 * 1056];  // 4 waves * 8 heads * 528 B

    const int wave = threadIdx.x >> 6;
    const int lane = threadIdx.x & 63;
    const int q = blockIdx.x * 4 + wave;
    const int b = blockIdx.y;
    const int rowq = b * NQ + q;
    const unsigned short* prow = proj + (size_t)rowq * 384;

    // ---- phase A: lane = h*8+i owns combos c = 2i, 2i+1 ----
    const int hA = lane >> 3;
    const int li = lane & 7;
    const int c0 = li * 2;

    const ushort2 lgu = *(const ushort2*)&prow[256 + hA * 16 + c0];
    const float lgx = b2f(lgu.x), lgy = b2f(lgu.y);
    float mx = fmaxf(lgx, lgy);
    mx = fmaxf(mx, __shfl_xor(mx, 1));
    mx = fmaxf(mx, __shfl_xor(mx, 2));
    mx = fmaxf(mx, __shfl_xor(mx, 4));
    const float e0 = __expf(lgx - mx);
    const float e1 = __expf(lgy - mx);
    float ssum = e0 + e1;
    ssum += __shfl_xor(ssum, 1);
    ssum += __shfl_xor(ssum, 2);
    ssum += __shfl_xor(ssum, 4);
    const float inv = 1.0f / ssum;

    const int l = c0 >> 2;   // both combos share the level
    const int Wl = (l == 0) ? 100 : (l == 1) ? 50 : (l == 2) ? 25 : 13;
    const int st = (l == 0) ? 0 : (l == 1) ? 10000 : (l == 2) ? 12500 : 13125;
    const int Hl = Wl;
    const float fW = (float)Wl, fH = (float)Hl;

    const float2 rxy = *(const float2*)&rp[((size_t)rowq * 4 + l) * 2];

    unsigned int* tbase = taps + wave * 1056 + hA * 132;

    #pragma unroll
    for (int cc = 0; cc < 2; ++cc) {
        const int c = c0 + cc;
        const ushort2 oxyu = *(const ushort2*)&prow[hA * 32 + c * 2];
        const float ox = b2f(oxyu.x), oy = b2f(oxyu.y);
        const float aww = (cc ? e1 : e0) * inv;
        const float x = fmaf(rxy.x, fW, ox) - 0.5f;
        const float y = fmaf(rxy.y, fH, oy) - 0.5f;
        const float x0f = floorf(x), y0f = floorf(y);
        const float fx = x - x0f, fy = y - y0f;
        const int ix = (int)x0f, iy = (int)y0f;
        const float wxv[2] = {1.f - fx, fx};
        const float wyv[2] = {1.f - fy, fy};

        unsigned int offv[4]; float wv_[4];
        #pragma unroll
        for (int tp = 0; tp < 4; ++tp) {
            const int dy = tp >> 1, dx = tp & 1;
            const int xi = ix + dx, yi = iy + dy;
            const bool ok = (xi >= 0) && (xi < Wl) && (yi >= 0) && (yi < Hl);
            const int cx = min(max(xi, 0), Wl - 1);
            const int cy = min(max(yi, 0), Hl - 1);
            offv[tp] = (unsigned int)(st + cy * Wl + cx) * 512u + (unsigned int)hA * 64u;
            wv_[tp]  = ok ? wyv[dy] * wxv[dx] * aww : 0.f;
        }
        const uint4 e0v = make_uint4(offv[0], offv[1], pk_bf16(wv_[0], wv_[1]), 0u);
        const uint4 e1v = make_uint4(offv[2], offv[3], pk_bf16(wv_[2], wv_[3]), 0u);
        *(uint4*)&tbase[c * 8]     = e0v;
        *(uint4*)&tbase[c * 8 + 4] = e1v;
    }

    // per-wave LDS drain (taps produced and consumed by this wave only)
    asm volatile("s_waitcnt lgkmcnt(0)" ::: "memory");

    // ---- phase B: lane = h*8+i owns dims i*4..i*4+3; saddr-form gathers ----
    const int h = lane >> 3;
    const unsigned int lane_off = (unsigned int)(lane & 7) * 8u;
    const char* vbase = (const char*)v + (size_t)b * NV * 512;   // wave-uniform
    const uint4* tp4 = (const uint4*)(taps + wave * 1056 + h * 132);

    float a0 = 0.f, a1 = 0.f, a2 = 0.f, a3 = 0.f;
    #pragma unroll 8
    for (int j = 0; j < 32; ++j) {
        const uint4 ee = tp4[j];
        const uint2 g0 = *(const uint2*)(vbase + (ee.x + lane_off));
        const uint2 g1 = *(const uint2*)(vbase + (ee.y + lane_off));
#if HAVE_DOT2
        bf16x2_t wpk; __builtin_memcpy(&wpk, &ee.z, 4);
        const unsigned int pl0 = __builtin_amdgcn_perm(g1.x, g0.x, 0x05040100u);
        const unsigned int ph0 = __builtin_amdgcn_perm(g1.x, g0.x, 0x07060302u);
        const unsigned int pl1 = __builtin_amdgcn_perm(g1.y, g0.y, 0x05040100u);
        const unsigned int ph1 = __builtin_amdgcn_perm(g1.y, g0.y, 0x07060302u);
        bf16x2_t v0, v1, v2, v3;
        __builtin_memcpy(&v0, &pl0, 4); __builtin_memcpy(&v1, &ph0, 4);
        __builtin_memcpy(&v2, &pl1, 4); __builtin_memcpy(&v3, &ph1, 4);
        a0 = __builtin_amdgcn_fdot2_f32_bf16(v0, wpk, a0, false);
        a1 = __builtin_amdgcn_fdot2_f32_bf16(v1, wpk, a1, false);
        a2 = __builtin_amdgcn_fdot2_f32_bf16(v2, wpk, a2, false);
        a3 = __builtin_amdgcn_fdot2_f32_bf16(v3, wpk, a3, false);
#else
        const float w0 = __uint_as_float(ee.z << 16);
        const float w1 = __uint_as_float(ee.z & 0xFFFF0000u);
        a0 = fmaf(w0, __uint_as_float(g0.x << 16), a0);
        a1 = fmaf(w0, __uint_as_float(g0.x & 0xFFFF0000u), a1);
        a2 = fmaf(w0, __uint_as_float(g0.y << 16), a2);
        a3 = fmaf(w0, __uint_as_float(g0.y & 0xFFFF0000u), a3);
        a0 = fmaf(w1, __uint_as_float(g1.x << 16), a0);
        a1 = fmaf(w1, __uint_as_float(g1.x & 0xFFFF0000u), a1);
        a2 = fmaf(w1, __uint_as_float(g1.y << 16), a2);
        a3 = fmaf(w1, __uint_as_float(g1.y & 0xFFFF0000u), a3);
#endif
    }

    ushort4 o;
    o.x = f2b(a0); o.y = f2b(a1); o.z = f2b(a2); o.w = f2b(a3);
    *(ushort4*)&out[(size_t)rowq * 256 + h * 32 + (lane & 7) * 4] = o;
}

// ---------------------------------------------------------------------------
// kernel_launch
// ---------------------------------------------------------------------------
extern "C" void kernel_launch(void* const* d_in, const int* in_sizes, int n_in,
                              void* d_out, int out_size, void* d_ws, size_t ws_size,
                              hipStream_t stream) {
    const float* query = (const float*)d_in[0];
    const float* value = (const float*)d_in[1];
    const float* rp    = (const float*)d_in[2];
    const float* Wv    = (const float*)d_in[4];
    const float* bv    = (const float*)d_in[5];
    const float* Woff  = (const float*)d_in[6];
    const float* boff  = (const float*)d_in[7];
    const float* Ww    = (const float*)d_in[8];
    const float* bw    = (const float*)d_in[9];
    const float* Wo    = (const float*)d_in[10];
    const float* bo    = (const float*)d_in[11];
    float* out = (float*)d_out;

    const int Mq = BS * NQ;   // 40000

    char* ws = (char*)d_ws;
    const size_t SZ_MSDA = (size_t)MQ_PAD * 256 * 2;   // padded rows
    const size_t SZ_VIN  = (size_t)MV_PAD * 256 * 2;   // bf16 value, padded
    const size_t SZ_QIN  = (size_t)MQ_PAD * 256 * 2;   // bf16 query, padded
    const size_t SZ_VPR  = (size_t)BS * NV * 256 * 2;  // projected v
    const size_t SZ_PROJ = (size_t)Mq * 384 * 2;

    unsigned short* msda  = (unsigned short*)(ws);
    unsigned short* v16   = (unsigned short*)(ws + SZ_MSDA);
    unsigned short* q16   = (unsigned short*)(ws + SZ_MSDA + SZ_VIN);
    unsigned short* v_prj = (unsigned short*)(ws + SZ_MSDA + SZ_VIN + SZ_QIN);
    unsigned short* proj  = (unsigned short*)(ws + SZ_MSDA + SZ_VIN + SZ_QIN + SZ_VPR);
    char* wp = ws + SZ_MSDA + SZ_VIN + SZ_QIN + SZ_VPR + SZ_PROJ;
    unsigned short* Wvt   = (unsigned short*)(wp);
    unsigned short* Wcatt = (unsigned short*)(wp + 256 * 256 * 2);
    unsigned short* Wot   = (unsigned short*)(wp + 256 * 256 * 2 + 384 * 256 * 2);
    float*          bcat  = (float*)(wp + 256 * 256 * 2 + 384 * 256 * 2 + 256 * 256 * 2);

    // weights transpose/cast + value/query fp32->bf16 streaming convert
    prep_convert<<<896 + CONV_BLOCKS, 256, 0, stream>>>(
        Wv, Woff, boff, Ww, bw, Wo, value, query,
        Wvt, Wcatt, Wot, bcat, v16, q16);

    // v_prj = v16 @ Wv + bv (bf16) AND proj = q16 @ [Woff|Ww] + bias (bf16)
    gemm_fused12<<<832 + 939, 256, 0, stream>>>(
        v16, q16, Wvt, Wcatt, bv, bcat, v_prj, proj);

    // softmax + sampling -> msda (bf16)
    msda_sample<<<dim3(NQ / 4, BS), 256, 0, stream>>>(v_prj, proj, rp, msda);

    // out = msda @ Wo + bo + query
    gemm_out<<<dim3((Mq + 127) / 128, 2), 256, 0, stream>>>(msda, Wot, bo, out, query);
}

// Round 4
// 315.967 us; speedup vs baseline: 1.1318x; 1.0006x over previous
//
#include <hip/hip_runtime.h>
#include <hip/hip_fp16.h>

#define BS     4
#define NQ     10000
#define NV     13294
#define EMBED  256
#define HEADS  8
#define LEVELS 4
#define POINTS 4
#define DH     32

// padded row counts (multiples of 128) so GEMM A-tiles can be read unguarded
#define MV_PAD 53248   // ceil(4*13294/128)*128
#define MQ_PAD 40064   // ceil(4*10000/128)*128

typedef __attribute__((ext_vector_type(8))) _Float16 half8;
typedef __attribute__((ext_vector_type(4))) float floatx4;

static __device__ __forceinline__ unsigned short f2h(float f) {
    __half h = __float2half(f);   // RNE
    return *(unsigned short*)&h;
}
static __device__ __forceinline__ float h2f(unsigned short u) {
    __half h = *(__half*)&u;
    return __half2float(h);
}
static __device__ __forceinline__ unsigned int pk_f16(float x, float y) {
    __half2 h = __floats2half2_rn(x, y);
    unsigned int u; __builtin_memcpy(&u, &h, 4); return u;
}

// async global->LDS, 16B per lane. LDS dest is wave-uniform base + lane*16.
static __device__ __forceinline__ void gload_lds16(const unsigned short* g, unsigned short* l) {
    __builtin_amdgcn_global_load_lds(
        (const __attribute__((address_space(1))) void*)g,
        (__attribute__((address_space(3))) void*)l,
        16, 0, 0);
}

// ---------------------------------------------------------------------------
// prep_convert:
//  blocks [0,896): weight transpose+cast (f16)
//  blocks [896, 896+CONV_BLOCKS): streaming fp32->f16 of value and query
// ---------------------------------------------------------------------------
#define CONV_BLOCKS 2048

__global__ __launch_bounds__(256) void prep_convert(
    const float* __restrict__ Wv,  const float* __restrict__ Woff,
    const float* __restrict__ boff,const float* __restrict__ Ww,
    const float* __restrict__ bw,  const float* __restrict__ Wo,
    const float* __restrict__ value, const float* __restrict__ query,
    unsigned short* __restrict__ Wvt, unsigned short* __restrict__ Wcatt,
    unsigned short* __restrict__ Wot, float* __restrict__ bcat,
    unsigned short* __restrict__ v16, unsigned short* __restrict__ q16)
{
    const int n = blockIdx.x;
    const int k = threadIdx.x;   // 0..255
    if (n < 896) {
        if (n < 256) {
            Wvt[n * 256 + k] = f2h(Wv[k * 256 + n]);
        } else if (n < 512) {
            Wcatt[(n - 256) * 256 + k] = f2h(Woff[k * 256 + (n - 256)]);
        } else if (n < 640) {
            Wcatt[(n - 256) * 256 + k] = f2h(Ww[k * 128 + (n - 512)]);
        } else {
            Wot[(n - 640) * 256 + k] = f2h(Wo[k * 256 + (n - 640)]);
        }
        if (n == 0) {
            for (int j = k; j < 384; j += 256)
                bcat[j] = (j < 256) ? boff[j] : bw[j - 256];
        }
        return;
    }
    // convert in units of 8 floats (two float4 loads -> one uint4 store)
    const long long NV8 = (long long)BS * NV * 256 / 8;   // 1,701,632
    const long long NQ8 = (long long)BS * NQ * 256 / 8;   // 1,280,000
    const long long stride = (long long)CONV_BLOCKS * 256;
    for (long long u = (long long)(n - 896) * 256 + k; u < NV8 + NQ8; u += stride) {
        const float4* s;
        unsigned short* d;
        if (u < NV8) { s = (const float4*)value + u * 2;         d = v16 + u * 8; }
        else         { s = (const float4*)query + (u - NV8) * 2; d = q16 + (u - NV8) * 8; }
        const float4 f0 = s[0], f1 = s[1];
        uint4 o;
        o.x = pk_f16(f0.x, f0.y);
        o.y = pk_f16(f0.z, f0.w);
        o.z = pk_f16(f1.x, f1.y);
        o.w = pk_f16(f1.z, f1.w);
        *(uint4*)d = o;
    }
}

// ---------------------------------------------------------------------------
// f16 MFMA GEMM body: C[M x N] = A[M x 256] @ Bt^T + bias (all f16 inputs).
// 128x128 tile / 256 threads / BK=64. m97 structure: global_load_lds width-16
// staging into linear LDS. Rule-21 both-sides XOR swizzle: inverse-swizzled
// global source + swizzled ds_read (byte ^= (row&7)<<4 within each 128B row).
// A must be padded so rows [mb*128, mb*128+128) are readable.
// MODE 0: f16 out; 2: fp32 out + residual.
// ---------------------------------------------------------------------------
template<int MODE>
static __device__ __forceinline__ void gemm_body(
    unsigned short* As, unsigned short* Bs,
    const unsigned short* __restrict__ A, int M,
    const unsigned short* __restrict__ Bt,
    const float* __restrict__ bias,
    void* __restrict__ Cv, int ldc,
    const float* __restrict__ residual,
    int mb, int nb)
{
    const int t    = threadIdx.x;
    const int w    = t >> 6;
    const int lane = t & 63;
    const int m0 = mb * 128;
    const int n0 = nb * 128;
    const int wm = (w & 1) * 64;
    const int wn = (w >> 1) * 64;
    const int lr = lane & 15;
    const int lk = (lane >> 4) * 8;

    // staging geometry: wave w, issue j covers LDS rows w*8+j*32 .. +8;
    // lane covers row w*8+j*32+(lane>>3), 16B chunk (lane&7).
    // Source column chunk pre-swizzled: chunk (lane&7)^(row&7), row&7=lane>>3.
    const int srow = w * 8 + (lane >> 3);
    const int scol = ((lane & 7) ^ (lane >> 3)) * 8;
    const unsigned short* ga = A  + (size_t)(m0 + srow) * 256 + scol;
    const unsigned short* gb = Bt + (size_t)(n0 + srow) * 256 + scol;
    unsigned short* lA = As + w * 512;   // + j*2048
    unsigned short* lB = Bs + w * 512;

    floatx4 acc[4][4] = {};

    for (int k0 = 0; k0 < 256; k0 += 64) {
        __syncthreads();   // previous tile's LDS reads complete before overwrite
        #pragma unroll
        for (int j = 0; j < 4; ++j) {
            gload_lds16(ga + (size_t)j * 32 * 256 + k0, lA + j * 2048);
            gload_lds16(gb + (size_t)j * 32 * 256 + k0, lB + j * 2048);
        }
        __syncthreads();   // vmcnt(0) drain: tile resident in LDS

        #pragma unroll
        for (int kk = 0; kk < 64; kk += 32) {
            half8 bf[4];
            #pragma unroll
            for (int nt = 0; nt < 4; ++nt) {
                const int row = wn + nt * 16 + lr;
                const int cb  = ((kk + lk) * 2) ^ ((row & 7) << 4);
                bf[nt] = *(const half8*)((const char*)Bs + row * 128 + cb);
            }
            #pragma unroll
            for (int mt = 0; mt < 4; ++mt) {
                const int row = wm + mt * 16 + lr;
                const int cb  = ((kk + lk) * 2) ^ ((row & 7) << 4);
                const half8 af = *(const half8*)((const char*)As + row * 128 + cb);
                #pragma unroll
                for (int nt = 0; nt < 4; ++nt)
                    acc[mt][nt] = __builtin_amdgcn_mfma_f32_16x16x32_f16(af, bf[nt], acc[mt][nt], 0, 0, 0);
            }
        }
    }

    // epilogue: C/D layout col = lane&15, row = (lane>>4)*4 + reg
    const int rbase = m0 + wm + (lane >> 4) * 4;
    #pragma unroll
    for (int nt = 0; nt < 4; ++nt) {
        const int col = n0 + wn + nt * 16 + lr;
        const float bb_ = bias[col];
        #pragma unroll
        for (int mt = 0; mt < 4; ++mt) {
            #pragma unroll
            for (int r = 0; r < 4; ++r) {
                const int row = rbase + mt * 16 + r;
                if (row < M) {
                    float val = acc[mt][nt][r] + bb_;
                    if (MODE == 2) val += residual[(size_t)row * ldc + col];
                    if (MODE == 0)
                        ((unsigned short*)Cv)[(size_t)row * ldc + col] = f2h(val);
                    else
                        ((float*)Cv)[(size_t)row * ldc + col] = val;
                }
            }
        }
    }
}

// Fused GEMM-V + GEMM-proj (independent, one dispatch to fill the machine).
// Work ids (after XCD-chunked swizzle):
//   [0, 832): v = v16 @ Wv + bv            (416 m-blocks x 2 n-blocks)
//   [832,1771): proj = q16 @ Wcat + bcat   (313 m-blocks x 3 n-blocks)
// Bijective chunked swizzle (m204): consecutive work ids (which share an
// A-row panel) execute on the SAME XCD -> A reuse hits that XCD's L2.
__global__ __launch_bounds__(256) void gemm_fused12(
    const unsigned short* __restrict__ v16, const unsigned short* __restrict__ q16,
    const unsigned short* __restrict__ Wvt, const unsigned short* __restrict__ Wcatt,
    const float* __restrict__ bv, const float* __restrict__ bcat,
    unsigned short* __restrict__ vout, unsigned short* __restrict__ projout)
{
    __shared__ __align__(16) unsigned short As[128 * 64];
    __shared__ __align__(16) unsigned short Bs[128 * 64];
    // nwg = 1771: q = 221, r = 3
    const unsigned int xcd = blockIdx.x & 7u, kk = blockIdx.x >> 3;
    const unsigned int wg = (xcd < 3u ? xcd * 222u : 3u * 222u + (xcd - 3u) * 221u) + kk;
    if (wg < 832u) {
        gemm_body<0>(As, Bs, v16, BS * NV, Wvt, bv, vout, 256, nullptr,
                     (int)(wg >> 1), (int)(wg & 1));
    } else {
        const unsigned int b2 = wg - 832u;
        gemm_body<0>(As, Bs, q16, BS * NQ, Wcatt, bcat, projout, 384, nullptr,
                     (int)(b2 / 3u), (int)(b2 % 3u));
    }
}

// out = msda @ Wo + bo + query  (fp32 out). 1D grid 626 + chunked swizzle.
__global__ __launch_bounds__(256) void gemm_out(
    const unsigned short* __restrict__ msda, const unsigned short* __restrict__ Wot,
    const float* __restrict__ bo, float* __restrict__ out,
    const float* __restrict__ query)
{
    __shared__ __align__(16) unsigned short As[128 * 64];
    __shared__ __align__(16) unsigned short Bs[128 * 64];
    // nwg = 626: q = 78, r = 2
    const unsigned int xcd = blockIdx.x & 7u, kk = blockIdx.x >> 3;
    const unsigned int wg = (xcd < 2u ? xcd * 79u : 2u * 79u + (xcd - 2u) * 78u) + kk;
    gemm_body<2>(As, Bs, msda, BS * NQ, Wot, bo, out, 256, query,
                 (int)(wg >> 1), (int)(wg & 1));
}

// ---------------------------------------------------------------------------
// Fused softmax + bilinear sampling (f16 pipeline).
// Tap entry (16 B): {off_tap0, off_tap1, pk(w0,w0), pk(w1,w1)} -- weights
// pre-broadcast as f16 pairs so phase B needs NO deinterleave perms:
// accumulation stays in packed-pair space via v_pk_fma_f16 (__hfma2).
// Taps are produced/consumed by the SAME wave -> per-wave lgkm drain only.
// ---------------------------------------------------------------------------
__global__ __launch_bounds__(256) void msda_sample(
    const unsigned short* __restrict__ v,
    const unsigned short* __restrict__ proj,
    const float* __restrict__ rp,
    unsigned short* __restrict__ out)
{
    __shared__ __align__(16) unsigned int taps[4 * 1056];  // 4 waves * 8 heads * 528 B

    const int wave = threadIdx.x >> 6;
    const int lane = threadIdx.x & 63;
    const int q = blockIdx.x * 4 + wave;
    const int b = blockIdx.y;
    const int rowq = b * NQ + q;
    const unsigned short* prow = proj + (size_t)rowq * 384;

    // ---- phase A: lane = h*8+i owns combos c = 2i, 2i+1 ----
    const int hA = lane >> 3;
    const int li = lane & 7;
    const int c0 = li * 2;

    const ushort2 lgu = *(const ushort2*)&prow[256 + hA * 16 + c0];
    const float lgx = h2f(lgu.x), lgy = h2f(lgu.y);
    float mx = fmaxf(lgx, lgy);
    mx = fmaxf(mx, __shfl_xor(mx, 1));
    mx = fmaxf(mx, __shfl_xor(mx, 2));
    mx = fmaxf(mx, __shfl_xor(mx, 4));
    const float e0 = __expf(lgx - mx);
    const float e1 = __expf(lgy - mx);
    float ssum = e0 + e1;
    ssum += __shfl_xor(ssum, 1);
    ssum += __shfl_xor(ssum, 2);
    ssum += __shfl_xor(ssum, 4);
    const float inv = 1.0f / ssum;

    const int l = c0 >> 2;   // both combos share the level
    const int Wl = (l == 0) ? 100 : (l == 1) ? 50 : (l == 2) ? 25 : 13;
    const int st = (l == 0) ? 0 : (l == 1) ? 10000 : (l == 2) ? 12500 : 13125;
    const int Hl = Wl;
    const float fW = (float)Wl, fH = (float)Hl;

    const float2 rxy = *(const float2*)&rp[((size_t)rowq * 4 + l) * 2];

    unsigned int* tbase = taps + wave * 1056 + hA * 132;

    #pragma unroll
    for (int cc = 0; cc < 2; ++cc) {
        const int c = c0 + cc;
        const ushort2 oxyu = *(const ushort2*)&prow[hA * 32 + c * 2];
        const float ox = h2f(oxyu.x), oy = h2f(oxyu.y);
        const float aww = (cc ? e1 : e0) * inv;
        const float x = fmaf(rxy.x, fW, ox) - 0.5f;
        const float y = fmaf(rxy.y, fH, oy) - 0.5f;
        const float x0f = floorf(x), y0f = floorf(y);
        const float fx = x - x0f, fy = y - y0f;
        const int ix = (int)x0f, iy = (int)y0f;
        const float wxv[2] = {1.f - fx, fx};
        const float wyv[2] = {1.f - fy, fy};

        unsigned int offv[4]; float wv_[4];
        #pragma unroll
        for (int tp = 0; tp < 4; ++tp) {
            const int dy = tp >> 1, dx = tp & 1;
            const int xi = ix + dx, yi = iy + dy;
            const bool ok = (xi >= 0) && (xi < Wl) && (yi >= 0) && (yi < Hl);
            const int cx = min(max(xi, 0), Wl - 1);
            const int cy = min(max(yi, 0), Hl - 1);
            offv[tp] = (unsigned int)(st + cy * Wl + cx) * 512u + (unsigned int)hA * 64u;
            wv_[tp]  = ok ? wyv[dy] * wxv[dx] * aww : 0.f;
        }
        const uint4 e0v = make_uint4(offv[0], offv[1], pk_f16(wv_[0], wv_[0]), pk_f16(wv_[1], wv_[1]));
        const uint4 e1v = make_uint4(offv[2], offv[3], pk_f16(wv_[2], wv_[2]), pk_f16(wv_[3], wv_[3]));
        *(uint4*)&tbase[c * 8]     = e0v;
        *(uint4*)&tbase[c * 8 + 4] = e1v;
    }

    // per-wave LDS drain (taps produced and consumed by this wave only)
    asm volatile("s_waitcnt lgkmcnt(0)" ::: "memory");

    // ---- phase B: lane = h*8+i owns dims i*4..i*4+3; packed-pair hfma2 ----
    const int h = lane >> 3;
    const unsigned int lane_off = (unsigned int)(lane & 7) * 8u;
    const char* vbase = (const char*)v + (size_t)b * NV * 512;   // wave-uniform
    const uint4* tp4 = (const uint4*)(taps + wave * 1056 + h * 132);

    __half2 a01 = __floats2half2_rn(0.f, 0.f);
    __half2 a23 = __floats2half2_rn(0.f, 0.f);
    #pragma unroll 8
    for (int j = 0; j < 32; ++j) {
        const uint4 ee = tp4[j];
        const uint2 g0 = *(const uint2*)(vbase + (ee.x + lane_off));
        const uint2 g1 = *(const uint2*)(vbase + (ee.y + lane_off));
        __half2 w0, w1, v0, v1, v2, v3;
        __builtin_memcpy(&w0, &ee.z, 4);
        __builtin_memcpy(&w1, &ee.w, 4);
        __builtin_memcpy(&v0, &g0.x, 4);
        __builtin_memcpy(&v1, &g0.y, 4);
        __builtin_memcpy(&v2, &g1.x, 4);
        __builtin_memcpy(&v3, &g1.y, 4);
        a01 = __hfma2(v0, w0, a01);
        a23 = __hfma2(v1, w0, a23);
        a01 = __hfma2(v2, w1, a01);
        a23 = __hfma2(v3, w1, a23);
    }

    uint2 o;
    __builtin_memcpy(&o.x, &a01, 4);
    __builtin_memcpy(&o.y, &a23, 4);
    *(uint2*)&out[(size_t)rowq * 256 + h * 32 + (lane & 7) * 4] = o;
}

// ---------------------------------------------------------------------------
// kernel_launch
// ---------------------------------------------------------------------------
extern "C" void kernel_launch(void* const* d_in, const int* in_sizes, int n_in,
                              void* d_out, int out_size, void* d_ws, size_t ws_size,
                              hipStream_t stream) {
    const float* query = (const float*)d_in[0];
    const float* value = (const float*)d_in[1];
    const float* rp    = (const float*)d_in[2];
    const float* Wv    = (const float*)d_in[4];
    const float* bv    = (const float*)d_in[5];
    const float* Woff  = (const float*)d_in[6];
    const float* boff  = (const float*)d_in[7];
    const float* Ww    = (const float*)d_in[8];
    const float* bw    = (const float*)d_in[9];
    const float* Wo    = (const float*)d_in[10];
    const float* bo    = (const float*)d_in[11];
    float* out = (float*)d_out;

    const int Mq = BS * NQ;   // 40000

    char* ws = (char*)d_ws;
    const size_t SZ_MSDA = (size_t)MQ_PAD * 256 * 2;   // padded rows
    const size_t SZ_VIN  = (size_t)MV_PAD * 256 * 2;   // f16 value, padded
    const size_t SZ_QIN  = (size_t)MQ_PAD * 256 * 2;   // f16 query, padded
    const size_t SZ_VPR  = (size_t)BS * NV * 256 * 2;  // projected v
    const size_t SZ_PROJ = (size_t)Mq * 384 * 2;

    unsigned short* msda  = (unsigned short*)(ws);
    unsigned short* v16   = (unsigned short*)(ws + SZ_MSDA);
    unsigned short* q16   = (unsigned short*)(ws + SZ_MSDA + SZ_VIN);
    unsigned short* v_prj = (unsigned short*)(ws + SZ_MSDA + SZ_VIN + SZ_QIN);
    unsigned short* proj  = (unsigned short*)(ws + SZ_MSDA + SZ_VIN + SZ_QIN + SZ_VPR);
    char* wp = ws + SZ_MSDA + SZ_VIN + SZ_QIN + SZ_VPR + SZ_PROJ;
    unsigned short* Wvt   = (unsigned short*)(wp);
    unsigned short* Wcatt = (unsigned short*)(wp + 256 * 256 * 2);
    unsigned short* Wot   = (unsigned short*)(wp + 256 * 256 * 2 + 384 * 256 * 2);
    float*          bcat  = (float*)(wp + 256 * 256 * 2 + 384 * 256 * 2 + 256 * 256 * 2);

    // weights transpose/cast + value/query fp32->f16 streaming convert
    prep_convert<<<896 + CONV_BLOCKS, 256, 0, stream>>>(
        Wv, Woff, boff, Ww, bw, Wo, value, query,
        Wvt, Wcatt, Wot, bcat, v16, q16);

    // v_prj = v16 @ Wv + bv (f16) AND proj = q16 @ [Woff|Ww] + bias (f16)
    gemm_fused12<<<832 + 939, 256, 0, stream>>>(
        v16, q16, Wvt, Wcatt, bv, bcat, v_prj, proj);

    // softmax + sampling -> msda (f16)
    msda_sample<<<dim3(NQ / 4, BS), 256, 0, stream>>>(v_prj, proj, rp, msda);

    // out = msda @ Wo + bo + query
    gemm_out<<<626, 256, 0, stream>>>(msda, Wot, bo, out, query);
}